// Round 1
// baseline (569.399 us; speedup 1.0000x reference)
//
#include <hip/hip_runtime.h>

typedef unsigned short u16;
typedef float f32x4 __attribute__((ext_vector_type(4)));
typedef short s16x8 __attribute__((ext_vector_type(8)));
typedef unsigned short u16x4 __attribute__((ext_vector_type(4)));

#define EPS 1e-6f

static __device__ __forceinline__ u16 f2bf(float f) {
  unsigned u = __float_as_uint(f);
  u += 0x7fffu + ((u >> 16) & 1u);   // RNE
  return (u16)(u >> 16);
}
static __device__ __forceinline__ float bf2f(u16 h) {
  return __uint_as_float(((unsigned)h) << 16);
}

// ---------------- Stage 1: transpose weights to bf16 [col][k] ----------------
__global__ void wtrans_kernel(const float* __restrict__ Wq, const float* __restrict__ Wk,
                              const float* __restrict__ Wv,
                              u16* __restrict__ WqT, u16* __restrict__ WkT, u16* __restrict__ WvT) {
  int b = blockIdx.x;
  int mat = b >> 4, cg = b & 15;
  const float* W = mat == 0 ? Wq : (mat == 1 ? Wk : Wv);
  u16* WT = mat == 0 ? WqT : (mat == 1 ? WkT : WvT);
  int t = threadIdx.x;
  int c = cg * 16 + (t & 15);
  int k0 = (t >> 4) * 16;
  for (int i = 0; i < 16; ++i) {
    int k = k0 + i;
    WT[c * 256 + k] = f2bf(W[k * 256 + c]);
  }
}

// ---------------- Stage 2: Q,K,V GEMMs ----------------
// Weights are L2-resident (384 KB total): B-fragments loaded DIRECTLY from
// global with one-chunk-ahead register prefetch. No weight LDS staging, no
// inner barriers -> waves run free. Q phases use swapped MFMA operands so the
// row-major Q store is vectorized (u16x4) instead of 64 scalar stores.
__global__ __launch_bounds__(256, 2)
void qkv_kernel(const float* __restrict__ x,
                const u16* __restrict__ WqT, const u16* __restrict__ WkT, const u16* __restrict__ WvT,
                const float* __restrict__ bq, const float* __restrict__ bk, const float* __restrict__ bv,
                u16* __restrict__ Qb, u16* __restrict__ Kt, u16* __restrict__ Vt,
                float* __restrict__ ksum, int N, int NPAD) {
  __shared__ u16 xs[128][264];   // x tile bf16, +8 pad
  __shared__ float ksl[256];     // block-local K column sums
  const int tid = threadIdx.x;
  const int n0 = blockIdx.x * 128;

  ksl[tid] = 0.f;

  // stage x tile (fp32 -> bf16), packed 8B LDS writes
  for (int i = 0; i < 32; ++i) {
    int l = tid + i * 256;
    int row = l >> 6;
    int c4 = (l & 63) << 2;
    int n = n0 + row;
    float4 v = make_float4(0.f, 0.f, 0.f, 0.f);
    if (n < N) v = *(const float4*)(x + (size_t)n * 256 + c4);
    u16x4 pk;
    pk[0] = f2bf(v.x); pk[1] = f2bf(v.y); pk[2] = f2bf(v.z); pk[3] = f2bf(v.w);
    *(u16x4*)&xs[row][c4] = pk;
  }
  __syncthreads();   // the ONLY block-wide barrier before the final ksum flush

  const int wave = tid >> 6, lane = tid & 63;
  const int quad = lane >> 4, l16 = lane & 15;
  const int wr = (wave >> 1) * 64;   // row (n) offset within tile
  const int wc = (wave & 1) * 64;    // col offset within 128-col half

  for (int ph = 0; ph < 6; ++ph) {
    const int mat = ph >> 1;
    const int colBase = (ph & 1) * 128;
    const u16* WT = mat == 0 ? WqT : (mat == 1 ? WkT : WvT);
    const u16* wp = WT + (size_t)(colBase + wc + l16) * 256 + quad * 8;

    f32x4 acc[4][4] = {};
    s16x8 b[4], bn[4];
#pragma unroll
    for (int f = 0; f < 4; ++f) b[f] = *(const s16x8*)(wp + f * 4096);

#pragma unroll
    for (int kc8 = 0; kc8 < 8; ++kc8) {
      const int ko = kc8 * 32;
      if (kc8 < 7) {
#pragma unroll
        for (int f = 0; f < 4; ++f) bn[f] = *(const s16x8*)(wp + f * 4096 + ko + 32);
      }
      s16x8 a[4];
#pragma unroll
      for (int f = 0; f < 4; ++f) a[f] = *(const s16x8*)&xs[wr + f * 16 + l16][ko + quad * 8];
      if (mat == 0) {
        // swapped operands: C row-index (quad*4+j) = weight column
#pragma unroll
        for (int fr = 0; fr < 4; ++fr)
#pragma unroll
          for (int fc = 0; fc < 4; ++fc)
            acc[fr][fc] = __builtin_amdgcn_mfma_f32_16x16x32_bf16(b[fr], a[fc], acc[fr][fc], 0, 0, 0);
      } else {
#pragma unroll
        for (int fr = 0; fr < 4; ++fr)
#pragma unroll
          for (int fc = 0; fc < 4; ++fc)
            acc[fr][fc] = __builtin_amdgcn_mfma_f32_16x16x32_bf16(a[fr], b[fc], acc[fr][fc], 0, 0, 0);
      }
#pragma unroll
      for (int f = 0; f < 4; ++f) b[f] = bn[f];
    }

    // ---- phase epilogue ----
    const float* bias = mat == 0 ? bq : (mat == 1 ? bk : bv);
    if (mat == 0) {
      // acc[fw][fx][j]: col = colBase+wc+fw*16+quad*4+j, row n = n0+wr+fx*16+l16
#pragma unroll
      for (int fw = 0; fw < 4; ++fw) {
        int colg4 = colBase + wc + fw * 16 + quad * 4;
        float4 bb = *(const float4*)(bias + colg4);
#pragma unroll
        for (int fx = 0; fx < 4; ++fx) {
          int n = n0 + wr + fx * 16 + l16;
          u16x4 pk;
          pk[0] = f2bf(fmaxf(acc[fw][fx][0] + bb.x, 0.f));
          pk[1] = f2bf(fmaxf(acc[fw][fx][1] + bb.y, 0.f));
          pk[2] = f2bf(fmaxf(acc[fw][fx][2] + bb.z, 0.f));
          pk[3] = f2bf(fmaxf(acc[fw][fx][3] + bb.w, 0.f));
          if (n >= N) { pk[0] = 0; pk[1] = 0; pk[2] = 0; pk[3] = 0; }
          *(u16x4*)&Qb[(size_t)n * 256 + colg4] = pk;
        }
      }
    } else {
      float ksacc[4] = {0.f, 0.f, 0.f, 0.f};
#pragma unroll
      for (int fc = 0; fc < 4; ++fc) {
        int colg = colBase + wc + fc * 16 + l16;
        float bb = bias[colg];
#pragma unroll
        for (int fr = 0; fr < 4; ++fr) {
          int n = n0 + wr + fr * 16 + quad * 4;
          u16x4 pk;
#pragma unroll
          for (int j = 0; j < 4; ++j) {
            float v = acc[fr][fc][j] + bb;
            if (mat == 1) v = fmaxf(v, 0.f);
            bool ok = (n + j < N);
            pk[j] = ok ? f2bf(v) : (u16)0;
            if (mat == 1) ksacc[fc] += ok ? v : 0.f;
          }
          u16* T = (mat == 1) ? Kt : Vt;
          *(u16x4*)&T[(size_t)colg * NPAD + n] = pk;
        }
      }
      if (mat == 1) {
#pragma unroll
        for (int fc = 0; fc < 4; ++fc) {
          float v = ksacc[fc];
          v += __shfl_xor(v, 16);
          v += __shfl_xor(v, 32);
          if (quad == 0) atomicAdd(&ksl[colBase + wc + fc * 16 + l16], v);
        }
      }
    }
  }
  __syncthreads();
  atomicAdd(&ksum[tid], ksl[tid]);
}

// ---------------- Stage 3: KV^T with fp32 atomic accumulation ----------------
// 128 n-splits x 4 tiles = 512 blocks (2/CU) for latency hiding; partials go
// straight into a 256KB fp32 buffer via atomicAdd (removes P + kvred traffic).
#define KVSPLIT 128
__global__ __launch_bounds__(256, 2)
void kv_kernel(const u16* __restrict__ Kt, const u16* __restrict__ Vt,
               float* __restrict__ KVf, int NPAD) {
  __shared__ u16 As[128][40];   // Vt rows (e), +8 pad
  __shared__ u16 Bs[128][40];   // Kt rows (d)
  const int tid = threadIdx.x;
  const int s = blockIdx.x & (KVSPLIT - 1);
  const int tile = blockIdx.x >> 7;
  const int ti = (tile >> 1) * 128;  // e base
  const int tj = (tile & 1) * 128;   // d base
  const int wave = tid >> 6, lane = tid & 63;
  const int quad = lane >> 4, l16 = lane & 15;
  const int we = (wave >> 1) * 64;
  const int wd = (wave & 1) * 64;
  f32x4 acc[4][4] = {};
  const int NCH = NPAD >> 5;

  int row0 = (tid * 2) >> 2, seg0 = ((tid * 2) & 3) * 8;
  int row1 = (tid * 2 + 1) >> 2, seg1 = ((tid * 2 + 1) & 3) * 8;

  s16x8 ra0, ra1, rb0, rb1;
  int c = s;
  if (c < NCH) {
    int nb = c << 5;
    ra0 = *(const s16x8*)&Vt[(size_t)(ti + row0) * NPAD + nb + seg0];
    ra1 = *(const s16x8*)&Vt[(size_t)(ti + row1) * NPAD + nb + seg1];
    rb0 = *(const s16x8*)&Kt[(size_t)(tj + row0) * NPAD + nb + seg0];
    rb1 = *(const s16x8*)&Kt[(size_t)(tj + row1) * NPAD + nb + seg1];
  }
  for (; c < NCH; c += KVSPLIT) {
    __syncthreads();
    *(s16x8*)&As[row0][seg0] = ra0;
    *(s16x8*)&As[row1][seg1] = ra1;
    *(s16x8*)&Bs[row0][seg0] = rb0;
    *(s16x8*)&Bs[row1][seg1] = rb1;
    __syncthreads();
    int cn = c + KVSPLIT;
    if (cn < NCH) {
      int nb = cn << 5;
      ra0 = *(const s16x8*)&Vt[(size_t)(ti + row0) * NPAD + nb + seg0];
      ra1 = *(const s16x8*)&Vt[(size_t)(ti + row1) * NPAD + nb + seg1];
      rb0 = *(const s16x8*)&Kt[(size_t)(tj + row0) * NPAD + nb + seg0];
      rb1 = *(const s16x8*)&Kt[(size_t)(tj + row1) * NPAD + nb + seg1];
    }
    s16x8 a[4], b[4];
#pragma unroll
    for (int f = 0; f < 4; ++f) a[f] = *(const s16x8*)&As[we + f * 16 + l16][quad * 8];
#pragma unroll
    for (int f = 0; f < 4; ++f) b[f] = *(const s16x8*)&Bs[wd + f * 16 + l16][quad * 8];
#pragma unroll
    for (int fr = 0; fr < 4; ++fr)
#pragma unroll
      for (int fc = 0; fc < 4; ++fc)
        acc[fr][fc] = __builtin_amdgcn_mfma_f32_16x16x32_bf16(a[fr], b[fc], acc[fr][fc], 0, 0, 0);
  }
#pragma unroll
  for (int fr = 0; fr < 4; ++fr)
#pragma unroll
    for (int fc = 0; fc < 4; ++fc) {
      int d = tj + wd + fc * 16 + l16;
      int e0 = ti + we + fr * 16 + quad * 4;
#pragma unroll
      for (int j = 0; j < 4; ++j)
        atomicAdd(&KVf[(size_t)d * 256 + e0 + j], acc[fr][fc][j]);
    }
}

// ---------------- Stage 4: convert fp32 KV -> bf16 KVtb[e][d] ----------------
__global__ void kvconv_kernel(const float* __restrict__ KVf, u16* __restrict__ KVtb) {
  int i = blockIdx.x * 256 + threadIdx.x;
  int e = i >> 8, d = i & 255;
  KVtb[i] = f2bf(KVf[(size_t)d * 256 + e]);
}

// ---------------- Stage 5: out[r][e] = (Q@KV)[r][e] / (Q[r].ksum + eps) ----------------
// KV (128KB, L2-resident) read DIRECTLY from global with register prefetch;
// Q staged once in LDS. No barriers in the main loop.
__global__ __launch_bounds__(256, 2)
void out_kernel(const u16* __restrict__ Qb, const u16* __restrict__ KVtb,
                const float* __restrict__ ksum, float* __restrict__ out,
                int N, int NPAD) {
  __shared__ u16 Qs[128][264];
  __shared__ float nrm[128];
  __shared__ float ks[256];
  __shared__ float nrmp[256];
  const int tid = threadIdx.x;
  const int r0 = blockIdx.x * 128;

  for (int i = 0; i < 16; ++i) {
    int l = tid + i * 256;
    int row = l >> 5;
    int seg = (l & 31) << 3;
    *(s16x8*)&Qs[row][seg] = *(const s16x8*)&Qb[(size_t)(r0 + row) * 256 + seg];
  }
  ks[tid] = ksum[tid];
  __syncthreads();

  // normalizer: 2 threads per row
  {
    int r = tid & 127, h = tid >> 7;
    float sa = 0.f;
    for (int d = h * 128; d < h * 128 + 128; d += 8) {
      s16x8 q = *(const s16x8*)&Qs[r][d];
#pragma unroll
      for (int j = 0; j < 8; ++j) sa += bf2f((u16)q[j]) * ks[d + j];
    }
    nrmp[tid] = sa;
  }
  __syncthreads();
  if (tid < 128) nrm[tid] = nrmp[tid] + nrmp[tid + 128] + EPS;
  __syncthreads();

  const int wave = tid >> 6, lane = tid & 63;
  const int quad = lane >> 4, l16 = lane & 15;
  const int we = (wave >> 1) * 64;    // e offset within 128-half
  const int wrw = (wave & 1) * 64;    // r offset
  const u16* ap = KVtb + (size_t)(we + l16) * 256 + quad * 8;

  s16x8 a[4], an[4];
#pragma unroll
  for (int f = 0; f < 4; ++f) a[f] = *(const s16x8*)(ap + f * 4096);

  for (int eh = 0; eh < 2; ++eh) {
    f32x4 acc[4][4] = {};
#pragma unroll
    for (int kc8 = 0; kc8 < 8; ++kc8) {
      const int ko = kc8 * 32;
      if (kc8 < 7) {
#pragma unroll
        for (int f = 0; f < 4; ++f) an[f] = *(const s16x8*)(ap + (size_t)(eh * 128 + f * 16) * 256 + ko + 32);
      } else if (eh == 0) {
#pragma unroll
        for (int f = 0; f < 4; ++f) an[f] = *(const s16x8*)(ap + (size_t)(128 + f * 16) * 256);
      }
      s16x8 b[4];
#pragma unroll
      for (int f = 0; f < 4; ++f) b[f] = *(const s16x8*)&Qs[wrw + f * 16 + l16][ko + quad * 8];
#pragma unroll
      for (int fr = 0; fr < 4; ++fr)
#pragma unroll
        for (int fc = 0; fc < 4; ++fc)
          acc[fr][fc] = __builtin_amdgcn_mfma_f32_16x16x32_bf16(a[fr], b[fc], acc[fr][fc], 0, 0, 0);
#pragma unroll
      for (int f = 0; f < 4; ++f) a[f] = an[f];
    }

    // epilogue for this e-half
#pragma unroll
    for (int fc = 0; fc < 4; ++fc) {
      int rl = wrw + fc * 16 + l16;
      int rg = r0 + rl;
      float inv = 1.0f / nrm[rl];
      if (rg < N) {
#pragma unroll
        for (int fr = 0; fr < 4; ++fr) {
          int eg = eh * 128 + we + fr * 16 + quad * 4;
          f32x4 o;
          o[0] = acc[fr][fc][0] * inv;
          o[1] = acc[fr][fc][1] * inv;
          o[2] = acc[fr][fc][2] * inv;
          o[3] = acc[fr][fc][3] * inv;
          *(f32x4*)&out[(size_t)rg * 256 + eg] = o;
        }
      }
    }
  }
}

extern "C" void kernel_launch(void* const* d_in, const int* in_sizes, int n_in,
                              void* d_out, int out_size, void* d_ws, size_t ws_size,
                              hipStream_t stream) {
  const float* x  = (const float*)d_in[0];
  const float* Wq = (const float*)d_in[1];
  const float* bq = (const float*)d_in[2];
  const float* Wk = (const float*)d_in[3];
  const float* bk = (const float*)d_in[4];
  const float* Wv = (const float*)d_in[5];
  const float* bv = (const float*)d_in[6];
  float* out = (float*)d_out;

  int N = in_sizes[0] / 256;
  int NPAD = ((N + 127) / 128) * 128;
  int nblk = NPAD / 128;

  char* p = (char*)d_ws;
  size_t szT = (size_t)256 * NPAD * sizeof(u16);
  u16* Kt = (u16*)p; p += szT;
  u16* Vt = (u16*)p; p += szT;
  u16* Qb = (u16*)p; p += szT;
  float* KVf = (float*)p; p += (size_t)65536 * sizeof(float);
  u16* KVtb = (u16*)p; p += (size_t)65536 * sizeof(u16);
  float* ksum = (float*)p; p += 256 * sizeof(float);
  u16* WqT = (u16*)p; p += (size_t)65536 * sizeof(u16);
  u16* WkT = (u16*)p; p += (size_t)65536 * sizeof(u16);
  u16* WvT = (u16*)p; p += (size_t)65536 * sizeof(u16);

  hipMemsetAsync(ksum, 0, 256 * sizeof(float), stream);
  hipMemsetAsync(KVf, 0, (size_t)65536 * sizeof(float), stream);
  wtrans_kernel<<<48, 256, 0, stream>>>(Wq, Wk, Wv, WqT, WkT, WvT);
  qkv_kernel<<<nblk, 256, 0, stream>>>(x, WqT, WkT, WvT, bq, bk, bv, Qb, Kt, Vt, ksum, N, NPAD);
  kv_kernel<<<KVSPLIT * 4, 256, 0, stream>>>(Kt, Vt, KVf, NPAD);
  kvconv_kernel<<<256, 256, 0, stream>>>(KVf, KVtb);
  out_kernel<<<nblk, 256, 0, stream>>>(Qb, KVtb, ksum, out, N, NPAD);
}

// Round 2
// 413.668 us; speedup vs baseline: 1.3765x; 1.3765x over previous
//
#include <hip/hip_runtime.h>

typedef unsigned short u16;
typedef float f32x4 __attribute__((ext_vector_type(4)));
typedef short s16x8 __attribute__((ext_vector_type(8)));
typedef unsigned short u16x4 __attribute__((ext_vector_type(4)));

#define EPS 1e-6f

static __device__ __forceinline__ u16 f2bf(float f) {
  unsigned u = __float_as_uint(f);
  u += 0x7fffu + ((u >> 16) & 1u);   // RNE
  return (u16)(u >> 16);
}
static __device__ __forceinline__ float bf2f(u16 h) {
  return __uint_as_float(((unsigned)h) << 16);
}

// ---------------- Stage 1: transpose weights to bf16 [col][k] ----------------
__global__ void wtrans_kernel(const float* __restrict__ Wq, const float* __restrict__ Wk,
                              const float* __restrict__ Wv,
                              u16* __restrict__ WqT, u16* __restrict__ WkT, u16* __restrict__ WvT) {
  int b = blockIdx.x;
  int mat = b >> 4, cg = b & 15;
  const float* W = mat == 0 ? Wq : (mat == 1 ? Wk : Wv);
  u16* WT = mat == 0 ? WqT : (mat == 1 ? WkT : WvT);
  int t = threadIdx.x;
  int c = cg * 16 + (t & 15);
  int k0 = (t >> 4) * 16;
  for (int i = 0; i < 16; ++i) {
    int k = k0 + i;
    WT[c * 256 + k] = f2bf(W[k * 256 + c]);
  }
}

// ---------------- Stage 2: Q,K,V GEMMs ----------------
// 256-row tile, 8 waves, 1 block/CU. Coalesced LDS weight staging with
// DOUBLE-buffered chunks + depth-2 register prefetch -> ONE barrier per
// 32-k chunk (R0 had two). Swapped-operand Q phases for vectorized Q stores.
__global__ __launch_bounds__(512, 2)
void qkv_kernel(const float* __restrict__ x,
                const u16* __restrict__ WqT, const u16* __restrict__ WkT, const u16* __restrict__ WvT,
                const float* __restrict__ bq, const float* __restrict__ bk, const float* __restrict__ bv,
                u16* __restrict__ Qb, u16* __restrict__ Kt, u16* __restrict__ Vt,
                float* __restrict__ ksum, int N, int NPAD) {
  __shared__ u16 xs[256][264];       // x tile bf16, +8 pad (135168 B)
  __shared__ u16 wst[2][128][40];    // double-buffered weight chunk (20480 B)
  __shared__ float ksl[256];         // block-local K column sums
  const int tid = threadIdx.x;
  const int n0 = blockIdx.x * 256;

  if (tid < 256) ksl[tid] = 0.f;

  // stage x tile (fp32 -> bf16), 32 float4 per thread
  for (int i = 0; i < 32; ++i) {
    int l = tid + i * 512;
    int row = l >> 6;
    int c4 = (l & 63) << 2;
    int n = n0 + row;
    float4 v = make_float4(0.f, 0.f, 0.f, 0.f);
    if (n < N) v = *(const float4*)(x + (size_t)n * 256 + c4);
    u16x4 pk;
    pk[0] = f2bf(v.x); pk[1] = f2bf(v.y); pk[2] = f2bf(v.z); pk[3] = f2bf(v.w);
    *(u16x4*)&xs[row][c4] = pk;
  }

  const int wave = tid >> 6, lane = tid & 63;
  const int quad = lane >> 4, l16 = lane & 15;
  const int wr = (wave >> 1) * 64;   // 4 row groups: 0,64,128,192
  const int wc = (wave & 1) * 64;    // 2 col groups within 128-col half

  // weight-chunk staging map: thread loads 16B: col = tid>>2, seg = (tid&3)*8
  const int scol = tid >> 2, sseg = (tid & 3) * 8;

  auto cptr = [&](int it) -> const u16* {
    int ph = it >> 3, kc = (it & 7) * 32;
    int mat = ph >> 1, colB = (ph & 1) * 128;
    const u16* WT = mat == 0 ? WqT : (mat == 1 ? WkT : WvT);
    return WT + (size_t)(colB + scol) * 256 + kc + sseg;
  };

#define QKV_MFMA(BUF, SWAP) { \
    s16x8 a[4], b[4]; \
    _Pragma("unroll") for (int f = 0; f < 4; ++f) a[f] = *(const s16x8*)&xs[wr + f * 16 + l16][kc + quad * 8]; \
    _Pragma("unroll") for (int f = 0; f < 4; ++f) b[f] = *(const s16x8*)&wst[BUF][wc + f * 16 + l16][quad * 8]; \
    if (SWAP) { \
      _Pragma("unroll") for (int fr = 0; fr < 4; ++fr) \
      _Pragma("unroll") for (int fc = 0; fc < 4; ++fc) \
        acc[fr][fc] = __builtin_amdgcn_mfma_f32_16x16x32_bf16(b[fr], a[fc], acc[fr][fc], 0, 0, 0); \
    } else { \
      _Pragma("unroll") for (int fr = 0; fr < 4; ++fr) \
      _Pragma("unroll") for (int fc = 0; fc < 4; ++fc) \
        acc[fr][fc] = __builtin_amdgcn_mfma_f32_16x16x32_bf16(a[fr], b[fc], acc[fr][fc], 0, 0, 0); \
    } }

  // prologue: chunks 0 and 1 into regs; chunk 0 into buffer 0
  s16x8 w0 = *(const s16x8*)cptr(0);
  s16x8 w1 = *(const s16x8*)cptr(1);
  *(s16x8*)&wst[0][scol][sseg] = w0;

  f32x4 acc[4][4] = {};
  for (int ii = 0; ii < 24; ++ii) {
    {   // even it: buffer 0, reg w0
      const int it = 2 * ii;
      const int kc = (it & 7) * 32;
      const bool swapQ = (it < 16);
      __syncthreads();                          // wst[0] ready (also covers xs at it==0)
      if (it < 46) w0 = *(const s16x8*)cptr(it + 2);
      QKV_MFMA(0, swapQ);
      *(s16x8*)&wst[1][scol][sseg] = w1;        // chunk it+1 -> buffer 1
    }
    {   // odd it: buffer 1, reg w1
      const int it = 2 * ii + 1;
      const int kc = (it & 7) * 32;
      const int ph = it >> 3;
      const int mat = ph >> 1, colBase = (ph & 1) * 128;
      __syncthreads();                          // wst[1] ready
      if (it < 46) w1 = *(const s16x8*)cptr(it + 2);
      QKV_MFMA(1, (mat == 0));
      if (it < 47) *(s16x8*)&wst[0][scol][sseg] = w0;   // chunk it+1 -> buffer 0

      if ((it & 7) == 7) {
        // ---- phase epilogue ----
        const float* bias = mat == 0 ? bq : (mat == 1 ? bk : bv);
        if (mat == 0) {
          // swapped: col = colBase+wc+fw*16+quad*4+j, row n = n0+wr+fx*16+l16
#pragma unroll
          for (int fw = 0; fw < 4; ++fw) {
            int colg4 = colBase + wc + fw * 16 + quad * 4;
            float4 bb = *(const float4*)(bias + colg4);
#pragma unroll
            for (int fx = 0; fx < 4; ++fx) {
              int n = n0 + wr + fx * 16 + l16;
              u16x4 pk;
              pk[0] = f2bf(fmaxf(acc[fw][fx][0] + bb.x, 0.f));
              pk[1] = f2bf(fmaxf(acc[fw][fx][1] + bb.y, 0.f));
              pk[2] = f2bf(fmaxf(acc[fw][fx][2] + bb.z, 0.f));
              pk[3] = f2bf(fmaxf(acc[fw][fx][3] + bb.w, 0.f));
              if (n >= N) { pk[0] = 0; pk[1] = 0; pk[2] = 0; pk[3] = 0; }
              *(u16x4*)&Qb[(size_t)n * 256 + colg4] = pk;
            }
          }
        } else {
          float ksacc[4] = {0.f, 0.f, 0.f, 0.f};
#pragma unroll
          for (int fc = 0; fc < 4; ++fc) {
            int colg = colBase + wc + fc * 16 + l16;
            float bb = bias[colg];
#pragma unroll
            for (int fr = 0; fr < 4; ++fr) {
              int n = n0 + wr + fr * 16 + quad * 4;
              u16x4 pk;
#pragma unroll
              for (int j = 0; j < 4; ++j) {
                float v = acc[fr][fc][j] + bb;
                if (mat == 1) v = fmaxf(v, 0.f);
                bool ok = (n + j < N);
                pk[j] = ok ? f2bf(v) : (u16)0;
                if (mat == 1) ksacc[fc] += ok ? v : 0.f;
              }
              u16* T = (mat == 1) ? Kt : Vt;
              *(u16x4*)&T[(size_t)colg * NPAD + n] = pk;
            }
          }
          if (mat == 1) {
#pragma unroll
            for (int fc = 0; fc < 4; ++fc) {
              float v = ksacc[fc];
              v += __shfl_xor(v, 16);
              v += __shfl_xor(v, 32);
              if (quad == 0) atomicAdd(&ksl[colBase + wc + fc * 16 + l16], v);
            }
          }
        }
#pragma unroll
        for (int fr = 0; fr < 4; ++fr)
#pragma unroll
          for (int fc = 0; fc < 4; ++fc)
            acc[fr][fc] = (f32x4){0.f, 0.f, 0.f, 0.f};
      }
    }
  }
  __syncthreads();
  if (tid < 256) atomicAdd(&ksum[tid], ksl[tid]);
}

// ---------------- Stage 3: KV^T partials, double-buffered (1 barrier/chunk) ----------------
__global__ __launch_bounds__(256, 2)
void kv_kernel(const u16* __restrict__ Kt, const u16* __restrict__ Vt,
               float* __restrict__ P, int NPAD, int kvsplit, int kvlog) {
  __shared__ u16 As[2][128][40];   // Vt rows (e)
  __shared__ u16 Bs[2][128][40];   // Kt rows (d)
  const int tid = threadIdx.x;
  const int s = blockIdx.x & (kvsplit - 1);
  const int tile = blockIdx.x >> kvlog;
  const int ti = (tile >> 1) * 128;  // e base
  const int tj = (tile & 1) * 128;   // d base
  const int wave = tid >> 6, lane = tid & 63;
  const int quad = lane >> 4, l16 = lane & 15;
  const int we = (wave >> 1) * 64;
  const int wd = (wave & 1) * 64;
  f32x4 acc[4][4] = {};
  const int NCH = NPAD >> 5;

  const int row0 = (tid * 2) >> 2, seg0 = ((tid * 2) & 3) * 8;
  const int row1 = (tid * 2 + 1) >> 2, seg1 = ((tid * 2 + 1) & 3) * 8;

  const int nit = (NCH - s + kvsplit - 1) / kvsplit;

#define KV_LOAD(C, RA0, RA1, RB0, RB1) { int nb = (C) << 5; \
    RA0 = *(const s16x8*)&Vt[(size_t)(ti + row0) * NPAD + nb + seg0]; \
    RA1 = *(const s16x8*)&Vt[(size_t)(ti + row1) * NPAD + nb + seg1]; \
    RB0 = *(const s16x8*)&Kt[(size_t)(tj + row0) * NPAD + nb + seg0]; \
    RB1 = *(const s16x8*)&Kt[(size_t)(tj + row1) * NPAD + nb + seg1]; }

#define KV_STORE(BUF, RA0, RA1, RB0, RB1) { \
    *(s16x8*)&As[BUF][row0][seg0] = RA0; *(s16x8*)&As[BUF][row1][seg1] = RA1; \
    *(s16x8*)&Bs[BUF][row0][seg0] = RB0; *(s16x8*)&Bs[BUF][row1][seg1] = RB1; }

#define KV_MFMA(BUF) { s16x8 a[4], b[4]; \
    _Pragma("unroll") for (int f = 0; f < 4; ++f) a[f] = *(const s16x8*)&As[BUF][we + f * 16 + l16][quad * 8]; \
    _Pragma("unroll") for (int f = 0; f < 4; ++f) b[f] = *(const s16x8*)&Bs[BUF][wd + f * 16 + l16][quad * 8]; \
    _Pragma("unroll") for (int fr = 0; fr < 4; ++fr) \
    _Pragma("unroll") for (int fc = 0; fc < 4; ++fc) \
      acc[fr][fc] = __builtin_amdgcn_mfma_f32_16x16x32_bf16(a[fr], b[fc], acc[fr][fc], 0, 0, 0); }

  s16x8 xa0, xa1, xb0, xb1, ya0, ya1, yb0, yb1;
  KV_LOAD(s, xa0, xa1, xb0, xb1);
  if (nit > 1) KV_LOAD(s + kvsplit, ya0, ya1, yb0, yb1);
  KV_STORE(0, xa0, xa1, xb0, xb1);

  int t = 0;
  for (; t + 1 < nit; t += 2) {
    __syncthreads();                        // buf0 ready
    if (t + 2 < nit) KV_LOAD(s + (t + 2) * kvsplit, xa0, xa1, xb0, xb1);
    KV_MFMA(0);
    KV_STORE(1, ya0, ya1, yb0, yb1);
    __syncthreads();                        // buf1 ready
    if (t + 3 < nit) KV_LOAD(s + (t + 3) * kvsplit, ya0, ya1, yb0, yb1);
    KV_MFMA(1);
    if (t + 2 < nit) KV_STORE(0, xa0, xa1, xb0, xb1);
  }
  if (t < nit) {                            // odd tail
    __syncthreads();
    KV_MFMA(0);
  }

  float* Pp = P + (size_t)s * 65536;
#pragma unroll
  for (int fr = 0; fr < 4; ++fr)
#pragma unroll
    for (int fc = 0; fc < 4; ++fc) {
      int d = tj + wd + fc * 16 + l16;
      int e0 = ti + we + fr * 16 + quad * 4;
      *(f32x4*)&Pp[(size_t)d * 256 + e0] = acc[fr][fc];
    }
}

// ---------------- Stage 4: reduce partials, emit KVtb[e][d] bf16 ----------------
__global__ void kvred_kernel(const float* __restrict__ P, u16* __restrict__ KVtb, int nsp) {
  int d = blockIdx.x;
  int e = threadIdx.x;
  float s = 0.f;
  for (int sp = 0; sp < nsp; ++sp) s += P[(size_t)sp * 65536 + d * 256 + e];
  KVtb[e * 256 + d] = f2bf(s);
}

// ---------------- Stage 5: out[r][e] = (Q@KV)[r][e] / (Q[r].ksum + eps) ----------------
__global__ __launch_bounds__(256, 2)
void out_kernel(const u16* __restrict__ Qb, const u16* __restrict__ KVtb,
                const float* __restrict__ ksum, float* __restrict__ out,
                int N, int NPAD) {
  __shared__ u16 Qs[128][264];
  __shared__ u16 KVs[128][40];
  __shared__ float nrm[128];
  __shared__ float ks[256];
  __shared__ float nrmp[256];
  const int tid = threadIdx.x;
  const int r0 = blockIdx.x * 128;

  for (int i = 0; i < 16; ++i) {
    int l = tid + i * 256;
    int row = l >> 5;
    int seg = (l & 31) << 3;
    *(s16x8*)&Qs[row][seg] = *(const s16x8*)&Qb[(size_t)(r0 + row) * 256 + seg];
  }
  ks[tid] = ksum[tid];
  __syncthreads();

  // normalizer: 2 threads per row
  {
    int r = tid & 127, h = tid >> 7;
    float sa = 0.f;
    for (int d = h * 128; d < h * 128 + 128; d += 8) {
      s16x8 q = *(const s16x8*)&Qs[r][d];
#pragma unroll
      for (int j = 0; j < 8; ++j) sa += bf2f((u16)q[j]) * ks[d + j];
    }
    nrmp[tid] = sa;
  }
  __syncthreads();
  if (tid < 128) nrm[tid] = nrmp[tid] + nrmp[tid + 128] + EPS;

  const int wave = tid >> 6, lane = tid & 63;
  const int quad = lane >> 4, l16 = lane & 15;
  const int we = (wave >> 1) * 64;    // e offset within 128-half
  const int wrw = (wave & 1) * 64;    // r offset
  const int scol = tid >> 1, sseg = (tid & 1) * 16;   // staging map

  s16x8 w0, w1;
  {
    const u16* p = KVtb + (size_t)scol * 256 + sseg;
    w0 = *(const s16x8*)p;
    w1 = *(const s16x8*)(p + 8);
  }

  f32x4 acc[4][4] = {};
  for (int it = 0; it < 16; ++it) {
    const int eh = it >> 3, kc = (it & 7) * 32;

    __syncthreads();
    *(s16x8*)&KVs[scol][sseg] = w0;
    *(s16x8*)&KVs[scol][sseg + 8] = w1;
    __syncthreads();

    if (it + 1 < 16) {
      int itn = it + 1;
      int ehn = itn >> 3, kcn = (itn & 7) * 32;
      const u16* p = KVtb + (size_t)(ehn * 128 + scol) * 256 + kcn + sseg;
      w0 = *(const s16x8*)p;
      w1 = *(const s16x8*)(p + 8);
    }

    s16x8 a[4], b[4];
#pragma unroll
    for (int f = 0; f < 4; ++f) a[f] = *(const s16x8*)&KVs[we + f * 16 + l16][quad * 8];
#pragma unroll
    for (int f = 0; f < 4; ++f) b[f] = *(const s16x8*)&Qs[wrw + f * 16 + l16][kc + quad * 8];
#pragma unroll
    for (int fr = 0; fr < 4; ++fr)
#pragma unroll
      for (int fc = 0; fc < 4; ++fc)
        acc[fr][fc] = __builtin_amdgcn_mfma_f32_16x16x32_bf16(a[fr], b[fc], acc[fr][fc], 0, 0, 0);

    if ((it & 7) == 7) {
#pragma unroll
      for (int fc = 0; fc < 4; ++fc) {
        int rl = wrw + fc * 16 + l16;
        int rg = r0 + rl;
        float inv = 1.0f / nrm[rl];
        if (rg < N) {
#pragma unroll
          for (int fr = 0; fr < 4; ++fr) {
            int eg = eh * 128 + we + fr * 16 + quad * 4;
            f32x4 o;
            o[0] = acc[fr][fc][0] * inv;
            o[1] = acc[fr][fc][1] * inv;
            o[2] = acc[fr][fc][2] * inv;
            o[3] = acc[fr][fc][3] * inv;
            *(f32x4*)&out[(size_t)rg * 256 + eg] = o;
          }
        }
      }
#pragma unroll
      for (int fr = 0; fr < 4; ++fr)
#pragma unroll
        for (int fc = 0; fc < 4; ++fc)
          acc[fr][fc] = (f32x4){0.f, 0.f, 0.f, 0.f};
    }
  }
}

extern "C" void kernel_launch(void* const* d_in, const int* in_sizes, int n_in,
                              void* d_out, int out_size, void* d_ws, size_t ws_size,
                              hipStream_t stream) {
  const float* x  = (const float*)d_in[0];
  const float* Wq = (const float*)d_in[1];
  const float* bq = (const float*)d_in[2];
  const float* Wk = (const float*)d_in[3];
  const float* bk = (const float*)d_in[4];
  const float* Wv = (const float*)d_in[5];
  const float* bv = (const float*)d_in[6];
  float* out = (float*)d_out;

  int N = in_sizes[0] / 256;
  int NPAD = ((N + 255) / 256) * 256;
  int nblkQ = NPAD / 256;
  int nblkO = NPAD / 128;

  size_t szT = (size_t)256 * NPAD * sizeof(u16);
  size_t fixed = 3 * szT + (size_t)65536 * sizeof(u16) + 256 * sizeof(float)
               + 3 * (size_t)65536 * sizeof(u16);
  int kvsplit = 128, kvlog = 7;
  if (fixed + (size_t)128 * 65536 * sizeof(float) > ws_size) { kvsplit = 64; kvlog = 6; }

  char* p = (char*)d_ws;
  u16* Kt = (u16*)p; p += szT;
  u16* Vt = (u16*)p; p += szT;
  u16* Qb = (u16*)p; p += szT;
  float* P = (float*)p; p += (size_t)kvsplit * 65536 * sizeof(float);
  u16* KVtb = (u16*)p; p += (size_t)65536 * sizeof(u16);
  float* ksum = (float*)p; p += 256 * sizeof(float);
  u16* WqT = (u16*)p; p += (size_t)65536 * sizeof(u16);
  u16* WkT = (u16*)p; p += (size_t)65536 * sizeof(u16);
  u16* WvT = (u16*)p; p += (size_t)65536 * sizeof(u16);

  hipMemsetAsync(ksum, 0, 256 * sizeof(float), stream);
  wtrans_kernel<<<48, 256, 0, stream>>>(Wq, Wk, Wv, WqT, WkT, WvT);
  qkv_kernel<<<nblkQ, 512, 0, stream>>>(x, WqT, WkT, WvT, bq, bk, bv, Qb, Kt, Vt, ksum, N, NPAD);
  kv_kernel<<<kvsplit * 4, 256, 0, stream>>>(Kt, Vt, P, NPAD, kvsplit, kvlog);
  kvred_kernel<<<256, 256, 0, stream>>>(P, KVtb, kvsplit);
  out_kernel<<<nblkO, 256, 0, stream>>>(Qb, KVtb, ksum, out, N, NPAD);
}